// Round 6
// baseline (596.216 us; speedup 1.0000x reference)
//
#include <hip/hip_runtime.h>
#include <hip/hip_bf16.h>

// EdgeBlock fused MLP:
//   out = relu(concat(edge, node[recv], node[send], g) @ W1 + b1) @ W2 + b2
// E=640000, N=10000, D=128, H=256, O=128.
//
// R6 = R5 algebra (per-node projection hoist) + persistent-block cross-tile
// software pipeline:
//   Pr[n] = node[n] @ W1[128:256] + hbias   (bf16, 5 MB)
//   Ps[n] = node[n] @ W1[256:384]           (bf16, 5 MB)
//   h     = relu(edge @ W1[0:128] + Pr[recv] + Ps[send])
// Main kernel: 768 persistent blocks x 256 thr, grid-stride over 10000
// 64-edge tiles. Edge loads for tile t+2 issue mid-iteration (full-iter
// latency budget); P gathers for tile t issue at iter top (hide under
// GEMM1); raw lgkmcnt(0)-only barriers (no vmcnt drain -> prefetches
// survive across barriers). 2 barriers/iter. LDS 48 KiB (Xe 16K + Hs 32K).

typedef __attribute__((ext_vector_type(8))) short bf16x8;
typedef __attribute__((ext_vector_type(4))) float f32x4;
typedef __attribute__((ext_vector_type(2))) unsigned int u32x2;

#define NTILE 10000
#define GRID  768

static __device__ __forceinline__ unsigned short f2bf(float f) {
    unsigned u = __builtin_bit_cast(unsigned, f);
    u += 0x7FFFu + ((u >> 16) & 1u);   // round-to-nearest-even
    return (unsigned short)(u >> 16);
}

static __device__ __forceinline__ unsigned cvt_pk_bf16(float lo, float hi) {
    unsigned r;
    asm("v_cvt_pk_bf16_f32 %0, %1, %2" : "=v"(r) : "v"(lo), "v"(hi));
    return r;
}

static __device__ __forceinline__ float bflo(unsigned u) {
    return __builtin_bit_cast(float, u << 16);
}
static __device__ __forceinline__ float bfhi(unsigned u) {
    return __builtin_bit_cast(float, u & 0xFFFF0000u);
}

// Barrier that waits only on LDS ops (cross-wave data flows only through
// LDS here). Avoids __syncthreads' vmcnt(0) drain, which would kill the
// cross-tile global-load prefetch. Pattern per learn_hip m201 template.
static __device__ __forceinline__ void block_sync_lds() {
    __builtin_amdgcn_sched_barrier(0);
    asm volatile("s_waitcnt lgkmcnt(0)" ::: "memory");
    __builtin_amdgcn_s_barrier();
    __builtin_amdgcn_sched_barrier(0);
}

// ---------------- prep kernels ----------------

// W1 [512][256] f32 -> fragment-packed bf16:
// block = gnt*12 + ks; lane l holds n = gnt*16 + (l&15), k = ks*32 + (l>>4)*8 + j.
__global__ void prep_w1_kernel(const float* __restrict__ W1,
                               ushort* __restrict__ w1f) {
    int id = blockIdx.x * 256 + threadIdx.x;  // 0..12287
    if (id >= 16 * 12 * 64) return;
    int l = id & 63, blk = id >> 6;
    int ks = blk % 12, gnt = blk / 12;
    int n  = gnt * 16 + (l & 15);
    int k0 = ks * 32 + (l >> 4) * 8;
    ushort tmp[8];
    #pragma unroll
    for (int j = 0; j < 8; ++j) tmp[j] = f2bf(W1[(k0 + j) * 256 + n]);
    *(bf16x8*)&w1f[(size_t)id * 8] = *(bf16x8*)tmp;
}

// W2 [256][128] f32 -> fragment-packed bf16 (8 n-tiles, 8 k-steps)
__global__ void prep_w2_kernel(const float* __restrict__ W2,
                               ushort* __restrict__ w2f) {
    int id = blockIdx.x * 256 + threadIdx.x;  // 0..4095
    if (id >= 8 * 8 * 64) return;
    int l = id & 63, blk = id >> 6;
    int ks = blk % 8, gnt = blk / 8;
    int n  = gnt * 16 + (l & 15);
    int k0 = ks * 32 + (l >> 4) * 8;
    ushort tmp[8];
    #pragma unroll
    for (int j = 0; j < 8; ++j) tmp[j] = f2bf(W2[(k0 + j) * 128 + n]);
    *(bf16x8*)&w2f[(size_t)id * 8] = *(bf16x8*)tmp;
}

// hbias[n] = b1[n] + sum_k g[k] * W1[384+k][n]   (fp32, exact global fold)
__global__ void prep_hbias_kernel(const float* __restrict__ W1,
                                  const float* __restrict__ b1,
                                  const float* __restrict__ g,
                                  float* __restrict__ hbias) {
    int n = threadIdx.x;  // 256 threads, 1 block
    float acc = b1[n];
    for (int k = 0; k < 128; ++k) acc += g[k] * W1[(384 + k) * 256 + n];
    hbias[n] = acc;
}

// Per-node projections: Pr[n] = node[n] @ W1[128:256] + hbias,
//                       Ps[n] = node[n] @ W1[256:384].  64 nodes/block.
__global__ __launch_bounds__(256) void prep_proj_kernel(
    const float* __restrict__ node_attr,   // [10000][128] f32
    const ushort* __restrict__ w1f,        // frag-packed (uses ks 4..11)
    const float* __restrict__ hbias,       // [256]
    ushort* __restrict__ Pr,               // [10000][256] bf16
    ushort* __restrict__ Ps)               // [10000][256] bf16
{
    __shared__ ushort Xn[64 * 128];   // swizzled node rows, bf16

    const int t = threadIdx.x, l = t & 63, wn = t >> 6;
    const int base = blockIdx.x * 64;
    const int lr = l & 15, q = l >> 4, lk = q * 8;

    #pragma unroll
    for (int p = 0; p < 4; ++p) {
        int chunk = p * 256 + t;
        int r  = chunk >> 4;
        int c0 = (chunk & 15) * 8;
        int node = base + r; if (node >= NTILE) node = NTILE - 1;
        const float4* src = (const float4*)(node_attr + (size_t)node * 128 + c0);
        float4 a = src[0];
        float4 b = src[1];
        uint4 uu = { cvt_pk_bf16(a.x, a.y), cvt_pk_bf16(a.z, a.w),
                     cvt_pk_bf16(b.x, b.y), cvt_pk_bf16(b.z, b.w) };
        *(bf16x8*)&Xn[r * 128 + (c0 ^ ((r & 7) << 3))] = __builtin_bit_cast(bf16x8, uu);
    }
    __syncthreads();

    #pragma unroll
    for (int s = 0; s < 2; ++s) {
        f32x4 acc[4][4];
        #pragma unroll
        for (int mt = 0; mt < 4; ++mt)
            #pragma unroll
            for (int nt = 0; nt < 4; ++nt)
                acc[mt][nt] = (f32x4){0.f, 0.f, 0.f, 0.f};

        #pragma unroll
        for (int ks = 0; ks < 4; ++ks) {
            bf16x8 B[4];
            #pragma unroll
            for (int nt = 0; nt < 4; ++nt)
                B[nt] = *(const bf16x8*)&w1f[
                    (size_t)(((wn * 4 + nt) * 12 + 4 + s * 4 + ks) * 64 + l) * 8];
            bf16x8 X[4];
            const int kk = ks * 32 + lk;
            #pragma unroll
            for (int mt = 0; mt < 4; ++mt) {
                const int row = mt * 16 + lr;
                X[mt] = *(const bf16x8*)&Xn[row * 128 + (kk ^ ((row & 7) << 3))];
            }
            #pragma unroll
            for (int mt = 0; mt < 4; ++mt)
                #pragma unroll
                for (int nt = 0; nt < 4; ++nt)
                    acc[mt][nt] = __builtin_amdgcn_mfma_f32_16x16x32_bf16(
                        B[nt], X[mt], acc[mt][nt], 0, 0, 0);
        }

        ushort* P = s ? Ps : Pr;
        #pragma unroll
        for (int nt = 0; nt < 4; ++nt) {
            const int F = wn * 64 + nt * 16 + q * 4;
            float4 hb4 = {0.f, 0.f, 0.f, 0.f};
            if (s == 0) hb4 = *(const float4*)&hbias[F];
            #pragma unroll
            for (int mt = 0; mt < 4; ++mt) {
                const int node = base + mt * 16 + lr;
                if (node < NTILE) {
                    u32x2 w = { cvt_pk_bf16(acc[mt][nt][0] + hb4.x,
                                            acc[mt][nt][1] + hb4.y),
                                cvt_pk_bf16(acc[mt][nt][2] + hb4.z,
                                            acc[mt][nt][3] + hb4.w) };
                    *(u32x2*)&P[(size_t)node * 256 + F] = w;
                }
            }
        }
    }
}

// ---------------- main fused kernel (persistent, pipelined) ----------------

__global__ __launch_bounds__(256, 2) void edge_mlp_kernel(
    const float* __restrict__ edge_attr,   // [E][128] f32
    const int* __restrict__ senders,
    const int* __restrict__ receivers,
    const ushort* __restrict__ w1f,        // frag-packed (uses ks 0..3)
    const ushort* __restrict__ w2f,        // frag-packed
    const ushort* __restrict__ Pr,         // [10000][256] bf16 (has hbias)
    const ushort* __restrict__ Ps,         // [10000][256] bf16
    const float* __restrict__ b2,          // [128]
    float* __restrict__ out)               // [E][128] f32
{
    __shared__ ushort Xe[64 * 128];   // 16 KiB, swizzled, tile-pipelined
    __shared__ ushort Hs[64 * 256];   // 32 KiB, swizzled

    const int t    = threadIdx.x;
    const int l    = t & 63;
    const int wid  = t >> 6;      // 0..3 : feat quarter
    const int lr = l & 15;        // edge within 16-tile (MFMA col)
    const int q  = l >> 4;        // lane quarter
    const int lk = q * 8;         // MFMA k sub-offset within 32

    // staging geometry: this thread's 4 chunks (row r, 8 floats at c0)
    int sr[4], sc[4];
    #pragma unroll
    for (int p = 0; p < 4; ++p) {
        int chunk = p * 256 + t;
        sr[p] = chunk >> 4;
        sc[p] = (chunk & 15) * 8;
    }

    // ---- prologue ----
    int ti = blockIdx.x;

    int recvC[4], sendC[4], recvN[4], sendN[4];
    #pragma unroll
    for (int mt = 0; mt < 4; ++mt) {
        int e = ti * 64 + mt * 16 + lr;
        recvC[mt] = receivers[e];
        sendC[mt] = senders[e];
    }

    float4 er[8];
    #pragma unroll
    for (int p = 0; p < 4; ++p) {
        const float4* src = (const float4*)(edge_attr + (size_t)(ti * 64 + sr[p]) * 128 + sc[p]);
        er[2 * p]     = src[0];
        er[2 * p + 1] = src[1];
    }
    #pragma unroll
    for (int p = 0; p < 4; ++p) {
        uint4 uu = { cvt_pk_bf16(er[2*p].x, er[2*p].y),  cvt_pk_bf16(er[2*p].z, er[2*p].w),
                     cvt_pk_bf16(er[2*p+1].x, er[2*p+1].y), cvt_pk_bf16(er[2*p+1].z, er[2*p+1].w) };
        *(bf16x8*)&Xe[sr[p] * 128 + (sc[p] ^ ((sr[p] & 7) << 3))] = __builtin_bit_cast(bf16x8, uu);
    }

    int tn = ti + GRID; if (tn >= NTILE) tn = ti;   // next tile (clamped)
    #pragma unroll
    for (int p = 0; p < 4; ++p) {
        const float4* src = (const float4*)(edge_attr + (size_t)(tn * 64 + sr[p]) * 128 + sc[p]);
        er[2 * p]     = src[0];
        er[2 * p + 1] = src[1];
    }
    #pragma unroll
    for (int mt = 0; mt < 4; ++mt) {
        int e = tn * 64 + mt * 16 + lr;
        recvN[mt] = receivers[e];
        sendN[mt] = senders[e];
    }

    block_sync_lds();   // Xe(t0) visible to all waves

    // ---- main loop ----
    for (; ti < NTILE; ti += GRID) {
        // P gathers for tile ti: 32 x 8B loads, resolve under GEMM1
        u32x2 pg[4][4], sg[4][4];
        #pragma unroll
        for (int nt = 0; nt < 4; ++nt) {
            const int F = wid * 64 + nt * 16 + q * 4;
            #pragma unroll
            for (int mt = 0; mt < 4; ++mt) {
                pg[nt][mt] = *(const u32x2*)&Pr[(size_t)recvC[mt] * 256 + F];
                sg[nt][mt] = *(const u32x2*)&Ps[(size_t)sendC[mt] * 256 + F];
            }
        }

        // GEMM1': D row = hidden feat, col = edge; K = 128 from Xe
        f32x4 acc[4][4];
        #pragma unroll
        for (int mt = 0; mt < 4; ++mt)
            #pragma unroll
            for (int nt = 0; nt < 4; ++nt)
                acc[mt][nt] = (f32x4){0.f, 0.f, 0.f, 0.f};

        bf16x8 B[2][4];
        #pragma unroll
        for (int nt = 0; nt < 4; ++nt)
            B[0][nt] = *(const bf16x8*)&w1f[(size_t)(((wid * 4 + nt) * 12 + 0) * 64 + l) * 8];

        #pragma unroll
        for (int ks = 0; ks < 4; ++ks) {
            const int cur = ks & 1;
            if (ks < 3) {
                #pragma unroll
                for (int nt = 0; nt < 4; ++nt)
                    B[cur ^ 1][nt] = *(const bf16x8*)&w1f[
                        (size_t)(((wid * 4 + nt) * 12 + (ks + 1)) * 64 + l) * 8];
            }
            bf16x8 X[4];
            const int kk = ks * 32 + lk;
            #pragma unroll
            for (int mt = 0; mt < 4; ++mt) {
                const int row = mt * 16 + lr;
                X[mt] = *(const bf16x8*)&Xe[row * 128 + (kk ^ ((row & 7) << 3))];
            }
            #pragma unroll
            for (int mt = 0; mt < 4; ++mt)
                #pragma unroll
                for (int nt = 0; nt < 4; ++nt)
                    acc[mt][nt] = __builtin_amdgcn_mfma_f32_16x16x32_bf16(
                        B[cur][nt], X[mt], acc[mt][nt], 0, 0, 0);
        }

        // epilogue 1: acc + Pr + Ps, relu, cvt_pk -> b64 swizzled Hs write
        #pragma unroll
        for (int nt = 0; nt < 4; ++nt) {
            const int F = wid * 64 + nt * 16 + q * 4;
            #pragma unroll
            for (int mt = 0; mt < 4; ++mt) {
                u32x2 p = pg[nt][mt], s = sg[nt][mt];
                float v0 = fmaxf(acc[mt][nt][0] + bflo(p.x) + bflo(s.x), 0.f);
                float v1 = fmaxf(acc[mt][nt][1] + bfhi(p.x) + bfhi(s.x), 0.f);
                float v2 = fmaxf(acc[mt][nt][2] + bflo(p.y) + bflo(s.y), 0.f);
                float v3 = fmaxf(acc[mt][nt][3] + bfhi(p.y) + bfhi(s.y), 0.f);
                u32x2 w = { cvt_pk_bf16(v0, v1), cvt_pk_bf16(v2, v3) };
                const int edge = mt * 16 + lr;
                *(u32x2*)&Hs[edge * 256 + (F ^ ((edge & 7) << 3))] = w;
            }
        }

        block_sync_lds();   // Hs ready; all waves' Xe(ti) reads complete

        // stage-write: Xe(tn) from er (compiler waits vmcnt on er here)
        #pragma unroll
        for (int p = 0; p < 4; ++p) {
            uint4 uu = { cvt_pk_bf16(er[2*p].x, er[2*p].y),  cvt_pk_bf16(er[2*p].z, er[2*p].w),
                         cvt_pk_bf16(er[2*p+1].x, er[2*p+1].y), cvt_pk_bf16(er[2*p+1].z, er[2*p+1].w) };
            *(bf16x8*)&Xe[sr[p] * 128 + (sc[p] ^ ((sr[p] & 7) << 3))] = __builtin_bit_cast(bf16x8, uu);
        }

        // prefetch tile tn2 = ti + 2*GRID (clamped): full-iteration latency
        int tn2 = ti + 2 * GRID; if (tn2 >= NTILE) tn2 = tn;
        #pragma unroll
        for (int p = 0; p < 4; ++p) {
            const float4* src = (const float4*)(edge_attr + (size_t)(tn2 * 64 + sr[p]) * 128 + sc[p]);
            er[2 * p]     = src[0];
            er[2 * p + 1] = src[1];
        }
        #pragma unroll
        for (int mt = 0; mt < 4; ++mt) {
            recvC[mt] = recvN[mt];
            sendC[mt] = sendN[mt];
            int e = tn2 * 64 + mt * 16 + lr;
            recvN[mt] = receivers[e];
            sendN[mt] = senders[e];
        }

        // GEMM2: D row = out feat, col = edge; K = 256 from Hs
        f32x4 acc2[4][2];
        #pragma unroll
        for (int mt = 0; mt < 4; ++mt)
            #pragma unroll
            for (int nt = 0; nt < 2; ++nt)
                acc2[mt][nt] = (f32x4){0.f, 0.f, 0.f, 0.f};

        bf16x8 W2b[2][2];
        #pragma unroll
        for (int nt = 0; nt < 2; ++nt)
            W2b[0][nt] = *(const bf16x8*)&w2f[(size_t)(((wid * 2 + nt) * 8 + 0) * 64 + l) * 8];

        #pragma unroll
        for (int ks = 0; ks < 8; ++ks) {
            const int cur = ks & 1;
            if (ks < 7) {
                #pragma unroll
                for (int nt = 0; nt < 2; ++nt)
                    W2b[cur ^ 1][nt] = *(const bf16x8*)&w2f[
                        (size_t)(((wid * 2 + nt) * 8 + (ks + 1)) * 64 + l) * 8];
            }
            bf16x8 Hfr[4];
            const int F = ks * 32 + lk;
            #pragma unroll
            for (int mt = 0; mt < 4; ++mt) {
                const int edge = mt * 16 + lr;
                Hfr[mt] = *(const bf16x8*)&Hs[edge * 256 + (F ^ ((edge & 7) << 3))];
            }
            #pragma unroll
            for (int mt = 0; mt < 4; ++mt)
                #pragma unroll
                for (int nt = 0; nt < 2; ++nt)
                    acc2[mt][nt] = __builtin_amdgcn_mfma_f32_16x16x32_bf16(
                        W2b[cur][nt], Hfr[mt], acc2[mt][nt], 0, 0, 0);
        }

        // epilogue 2: +b2, dwordx4 stores
        #pragma unroll
        for (int nt = 0; nt < 2; ++nt) {
            const int F = wid * 32 + nt * 16 + q * 4;
            float4 b24 = *(const float4*)&b2[F];
            #pragma unroll
            for (int mt = 0; mt < 4; ++mt) {
                float4 o = { acc2[mt][nt][0] + b24.x, acc2[mt][nt][1] + b24.y,
                             acc2[mt][nt][2] + b24.z, acc2[mt][nt][3] + b24.w };
                *(float4*)&out[(size_t)(ti * 64 + mt * 16 + lr) * 128 + F] = o;
            }
        }

        tn = tn2;
        block_sync_lds();   // Xe(next tile) visible before next GEMM1
    }
}

// ---------------- launcher ----------------

extern "C" void kernel_launch(void* const* d_in, const int* in_sizes, int n_in,
                              void* d_out, int out_size, void* d_ws, size_t ws_size,
                              hipStream_t stream) {
    (void)in_sizes; (void)n_in; (void)out_size; (void)ws_size;

    const float* edge_attr   = (const float*)d_in[0];  // [640000][128]
    const float* node_attr   = (const float*)d_in[1];  // [10000][128]
    const float* global_attr = (const float*)d_in[2];  // [128]
    const int*   senders     = (const int*)d_in[3];
    const int*   receivers   = (const int*)d_in[4];
    const float* W1          = (const float*)d_in[5];  // [512][256]
    const float* b1          = (const float*)d_in[6];  // [256]
    const float* W2          = (const float*)d_in[7];  // [256][128]
    const float* b2          = (const float*)d_in[8];  // [128]
    float* out = (float*)d_out;

    // workspace layout (all 16B aligned)
    ushort* w1f   = (ushort*)d_ws;                          //   196,608 B
    ushort* w2f   = (ushort*)((char*)d_ws + 196608);        //    65,536 B
    float*  hbias = (float*)((char*)d_ws + 262144);         //     1,024 B
    ushort* Pr    = (ushort*)((char*)d_ws + 263168);        // 5,120,000 B
    ushort* Ps    = (ushort*)((char*)d_ws + 5383168);       // 5,120,000 B

    hipLaunchKernelGGL(prep_w1_kernel,    dim3(48),  dim3(256), 0, stream, W1, w1f);
    hipLaunchKernelGGL(prep_w2_kernel,    dim3(16),  dim3(256), 0, stream, W2, w2f);
    hipLaunchKernelGGL(prep_hbias_kernel, dim3(1),   dim3(256), 0, stream, W1, b1, global_attr, hbias);
    hipLaunchKernelGGL(prep_proj_kernel,  dim3(157), dim3(256), 0, stream,
                       node_attr, w1f, hbias, Pr, Ps);

    hipLaunchKernelGGL(edge_mlp_kernel, dim3(GRID), dim3(256), 0, stream,
                       edge_attr, senders, receivers, w1f, w2f, Pr, Ps, b2, out);
}

// Round 7
// 361.292 us; speedup vs baseline: 1.6502x; 1.6502x over previous
//
#include <hip/hip_runtime.h>
#include <hip/hip_bf16.h>

// EdgeBlock fused MLP:
//   out = relu(concat(edge, node[recv], node[send], g) @ W1 + b1) @ W2 + b2
// E=640000, N=10000, D=128, H=256, O=128.
//
// R7 = R6 (persistent blocks + cross-tile software pipeline) with the spill
// fixed: launch_bounds(256,1) lets the allocator hold the pipeline state
// (~200 VGPR: acc 64 + W-dbuf 32 + er prefetch 32 + gathers 32 + indices)
// without scratch. R6's 128-VGPR cap spilled ~70 regs -> +450 MB HBM.
//   Pr[n] = node[n] @ W1[128:256] + hbias   (bf16, 5 MB)
//   Ps[n] = node[n] @ W1[256:384]           (bf16, 5 MB)
//   h     = relu(edge @ W1[0:128] + Pr[recv] + Ps[send])
// 768 persistent blocks x 256 thr grid-stride over 10000 64-edge tiles;
// edge loads for t+2 issued mid-iteration; P gathers at iter top resolve
// under GEMM1; lgkmcnt-only barriers keep prefetches in flight. LDS 48 KiB.

typedef __attribute__((ext_vector_type(8))) short bf16x8;
typedef __attribute__((ext_vector_type(4))) float f32x4;
typedef __attribute__((ext_vector_type(2))) unsigned int u32x2;

#define NTILE 10000
#define GRID  768

static __device__ __forceinline__ unsigned short f2bf(float f) {
    unsigned u = __builtin_bit_cast(unsigned, f);
    u += 0x7FFFu + ((u >> 16) & 1u);   // round-to-nearest-even
    return (unsigned short)(u >> 16);
}

static __device__ __forceinline__ unsigned cvt_pk_bf16(float lo, float hi) {
    unsigned r;
    asm("v_cvt_pk_bf16_f32 %0, %1, %2" : "=v"(r) : "v"(lo), "v"(hi));
    return r;
}

static __device__ __forceinline__ float bflo(unsigned u) {
    return __builtin_bit_cast(float, u << 16);
}
static __device__ __forceinline__ float bfhi(unsigned u) {
    return __builtin_bit_cast(float, u & 0xFFFF0000u);
}

// Barrier that waits only on LDS ops (cross-wave data flows only through
// LDS here). Avoids __syncthreads' vmcnt(0) drain, which would kill the
// cross-tile global-load prefetch. Pattern per learn_hip m201 template.
static __device__ __forceinline__ void block_sync_lds() {
    __builtin_amdgcn_sched_barrier(0);
    asm volatile("s_waitcnt lgkmcnt(0)" ::: "memory");
    __builtin_amdgcn_s_barrier();
    __builtin_amdgcn_sched_barrier(0);
}

// ---------------- prep kernels ----------------

// W1 [512][256] f32 -> fragment-packed bf16:
// block = gnt*12 + ks; lane l holds n = gnt*16 + (l&15), k = ks*32 + (l>>4)*8 + j.
__global__ void prep_w1_kernel(const float* __restrict__ W1,
                               ushort* __restrict__ w1f) {
    int id = blockIdx.x * 256 + threadIdx.x;  // 0..12287
    if (id >= 16 * 12 * 64) return;
    int l = id & 63, blk = id >> 6;
    int ks = blk % 12, gnt = blk / 12;
    int n  = gnt * 16 + (l & 15);
    int k0 = ks * 32 + (l >> 4) * 8;
    ushort tmp[8];
    #pragma unroll
    for (int j = 0; j < 8; ++j) tmp[j] = f2bf(W1[(k0 + j) * 256 + n]);
    *(bf16x8*)&w1f[(size_t)id * 8] = *(bf16x8*)tmp;
}

// W2 [256][128] f32 -> fragment-packed bf16 (8 n-tiles, 8 k-steps)
__global__ void prep_w2_kernel(const float* __restrict__ W2,
                               ushort* __restrict__ w2f) {
    int id = blockIdx.x * 256 + threadIdx.x;  // 0..4095
    if (id >= 8 * 8 * 64) return;
    int l = id & 63, blk = id >> 6;
    int ks = blk % 8, gnt = blk / 8;
    int n  = gnt * 16 + (l & 15);
    int k0 = ks * 32 + (l >> 4) * 8;
    ushort tmp[8];
    #pragma unroll
    for (int j = 0; j < 8; ++j) tmp[j] = f2bf(W2[(k0 + j) * 128 + n]);
    *(bf16x8*)&w2f[(size_t)id * 8] = *(bf16x8*)tmp;
}

// hbias[n] = b1[n] + sum_k g[k] * W1[384+k][n]   (fp32, exact global fold)
__global__ void prep_hbias_kernel(const float* __restrict__ W1,
                                  const float* __restrict__ b1,
                                  const float* __restrict__ g,
                                  float* __restrict__ hbias) {
    int n = threadIdx.x;  // 256 threads, 1 block
    float acc = b1[n];
    for (int k = 0; k < 128; ++k) acc += g[k] * W1[(384 + k) * 256 + n];
    hbias[n] = acc;
}

// Per-node projections: Pr[n] = node[n] @ W1[128:256] + hbias,
//                       Ps[n] = node[n] @ W1[256:384].  64 nodes/block.
__global__ __launch_bounds__(256) void prep_proj_kernel(
    const float* __restrict__ node_attr,   // [10000][128] f32
    const ushort* __restrict__ w1f,        // frag-packed (uses ks 4..11)
    const float* __restrict__ hbias,       // [256]
    ushort* __restrict__ Pr,               // [10000][256] bf16
    ushort* __restrict__ Ps)               // [10000][256] bf16
{
    __shared__ ushort Xn[64 * 128];   // swizzled node rows, bf16

    const int t = threadIdx.x, l = t & 63, wn = t >> 6;
    const int base = blockIdx.x * 64;
    const int lr = l & 15, q = l >> 4, lk = q * 8;

    #pragma unroll
    for (int p = 0; p < 4; ++p) {
        int chunk = p * 256 + t;
        int r  = chunk >> 4;
        int c0 = (chunk & 15) * 8;
        int node = base + r; if (node >= NTILE) node = NTILE - 1;
        const float4* src = (const float4*)(node_attr + (size_t)node * 128 + c0);
        float4 a = src[0];
        float4 b = src[1];
        uint4 uu = { cvt_pk_bf16(a.x, a.y), cvt_pk_bf16(a.z, a.w),
                     cvt_pk_bf16(b.x, b.y), cvt_pk_bf16(b.z, b.w) };
        *(bf16x8*)&Xn[r * 128 + (c0 ^ ((r & 7) << 3))] = __builtin_bit_cast(bf16x8, uu);
    }
    __syncthreads();

    #pragma unroll
    for (int s = 0; s < 2; ++s) {
        f32x4 acc[4][4];
        #pragma unroll
        for (int mt = 0; mt < 4; ++mt)
            #pragma unroll
            for (int nt = 0; nt < 4; ++nt)
                acc[mt][nt] = (f32x4){0.f, 0.f, 0.f, 0.f};

        #pragma unroll
        for (int ks = 0; ks < 4; ++ks) {
            bf16x8 B[4];
            #pragma unroll
            for (int nt = 0; nt < 4; ++nt)
                B[nt] = *(const bf16x8*)&w1f[
                    (size_t)(((wn * 4 + nt) * 12 + 4 + s * 4 + ks) * 64 + l) * 8];
            bf16x8 X[4];
            const int kk = ks * 32 + lk;
            #pragma unroll
            for (int mt = 0; mt < 4; ++mt) {
                const int row = mt * 16 + lr;
                X[mt] = *(const bf16x8*)&Xn[row * 128 + (kk ^ ((row & 7) << 3))];
            }
            #pragma unroll
            for (int mt = 0; mt < 4; ++mt)
                #pragma unroll
                for (int nt = 0; nt < 4; ++nt)
                    acc[mt][nt] = __builtin_amdgcn_mfma_f32_16x16x32_bf16(
                        B[nt], X[mt], acc[mt][nt], 0, 0, 0);
        }

        ushort* P = s ? Ps : Pr;
        #pragma unroll
        for (int nt = 0; nt < 4; ++nt) {
            const int F = wn * 64 + nt * 16 + q * 4;
            float4 hb4 = {0.f, 0.f, 0.f, 0.f};
            if (s == 0) hb4 = *(const float4*)&hbias[F];
            #pragma unroll
            for (int mt = 0; mt < 4; ++mt) {
                const int node = base + mt * 16 + lr;
                if (node < NTILE) {
                    u32x2 w = { cvt_pk_bf16(acc[mt][nt][0] + hb4.x,
                                            acc[mt][nt][1] + hb4.y),
                                cvt_pk_bf16(acc[mt][nt][2] + hb4.z,
                                            acc[mt][nt][3] + hb4.w) };
                    *(u32x2*)&P[(size_t)node * 256 + F] = w;
                }
            }
        }
    }
}

// ---------------- main fused kernel (persistent, pipelined) ----------------

__global__ __launch_bounds__(256, 1) void edge_mlp_kernel(
    const float* __restrict__ edge_attr,   // [E][128] f32
    const int* __restrict__ senders,
    const int* __restrict__ receivers,
    const ushort* __restrict__ w1f,        // frag-packed (uses ks 0..3)
    const ushort* __restrict__ w2f,        // frag-packed
    const ushort* __restrict__ Pr,         // [10000][256] bf16 (has hbias)
    const ushort* __restrict__ Ps,         // [10000][256] bf16
    const float* __restrict__ b2,          // [128]
    float* __restrict__ out)               // [E][128] f32
{
    __shared__ ushort Xe[64 * 128];   // 16 KiB, swizzled, tile-pipelined
    __shared__ ushort Hs[64 * 256];   // 32 KiB, swizzled

    const int t    = threadIdx.x;
    const int l    = t & 63;
    const int wid  = t >> 6;      // 0..3 : feat quarter
    const int lr = l & 15;        // edge within 16-tile (MFMA col)
    const int q  = l >> 4;        // lane quarter
    const int lk = q * 8;         // MFMA k sub-offset within 32

    // staging geometry: this thread's 4 chunks (row r, 8 floats at c0)
    int sr[4], sc[4];
    #pragma unroll
    for (int p = 0; p < 4; ++p) {
        int chunk = p * 256 + t;
        sr[p] = chunk >> 4;
        sc[p] = (chunk & 15) * 8;
    }

    // ---- prologue ----
    int ti = blockIdx.x;

    int recvC[4], sendC[4], recvN[4], sendN[4];
    #pragma unroll
    for (int mt = 0; mt < 4; ++mt) {
        int e = ti * 64 + mt * 16 + lr;
        recvC[mt] = receivers[e];
        sendC[mt] = senders[e];
    }

    float4 er[8];
    #pragma unroll
    for (int p = 0; p < 4; ++p) {
        const float4* src = (const float4*)(edge_attr + (size_t)(ti * 64 + sr[p]) * 128 + sc[p]);
        er[2 * p]     = src[0];
        er[2 * p + 1] = src[1];
    }
    #pragma unroll
    for (int p = 0; p < 4; ++p) {
        uint4 uu = { cvt_pk_bf16(er[2*p].x, er[2*p].y),  cvt_pk_bf16(er[2*p].z, er[2*p].w),
                     cvt_pk_bf16(er[2*p+1].x, er[2*p+1].y), cvt_pk_bf16(er[2*p+1].z, er[2*p+1].w) };
        *(bf16x8*)&Xe[sr[p] * 128 + (sc[p] ^ ((sr[p] & 7) << 3))] = __builtin_bit_cast(bf16x8, uu);
    }

    int tn = ti + GRID; if (tn >= NTILE) tn = ti;   // next tile (clamped)
    #pragma unroll
    for (int p = 0; p < 4; ++p) {
        const float4* src = (const float4*)(edge_attr + (size_t)(tn * 64 + sr[p]) * 128 + sc[p]);
        er[2 * p]     = src[0];
        er[2 * p + 1] = src[1];
    }
    #pragma unroll
    for (int mt = 0; mt < 4; ++mt) {
        int e = tn * 64 + mt * 16 + lr;
        recvN[mt] = receivers[e];
        sendN[mt] = senders[e];
    }

    block_sync_lds();   // Xe(t0) visible to all waves

    // ---- main loop ----
    for (; ti < NTILE; ti += GRID) {
        // P gathers for tile ti: 32 x 8B loads, resolve under GEMM1
        u32x2 pg[4][4], sg[4][4];
        #pragma unroll
        for (int nt = 0; nt < 4; ++nt) {
            const int F = wid * 64 + nt * 16 + q * 4;
            #pragma unroll
            for (int mt = 0; mt < 4; ++mt) {
                pg[nt][mt] = *(const u32x2*)&Pr[(size_t)recvC[mt] * 256 + F];
                sg[nt][mt] = *(const u32x2*)&Ps[(size_t)sendC[mt] * 256 + F];
            }
        }

        // GEMM1': D row = hidden feat, col = edge; K = 128 from Xe
        f32x4 acc[4][4];
        #pragma unroll
        for (int mt = 0; mt < 4; ++mt)
            #pragma unroll
            for (int nt = 0; nt < 4; ++nt)
                acc[mt][nt] = (f32x4){0.f, 0.f, 0.f, 0.f};

        bf16x8 B[2][4];
        #pragma unroll
        for (int nt = 0; nt < 4; ++nt)
            B[0][nt] = *(const bf16x8*)&w1f[(size_t)(((wid * 4 + nt) * 12 + 0) * 64 + l) * 8];

        #pragma unroll
        for (int ks = 0; ks < 4; ++ks) {
            const int cur = ks & 1;
            if (ks < 3) {
                #pragma unroll
                for (int nt = 0; nt < 4; ++nt)
                    B[cur ^ 1][nt] = *(const bf16x8*)&w1f[
                        (size_t)(((wid * 4 + nt) * 12 + (ks + 1)) * 64 + l) * 8];
            }
            bf16x8 X[4];
            const int kk = ks * 32 + lk;
            #pragma unroll
            for (int mt = 0; mt < 4; ++mt) {
                const int row = mt * 16 + lr;
                X[mt] = *(const bf16x8*)&Xe[row * 128 + (kk ^ ((row & 7) << 3))];
            }
            #pragma unroll
            for (int mt = 0; mt < 4; ++mt)
                #pragma unroll
                for (int nt = 0; nt < 4; ++nt)
                    acc[mt][nt] = __builtin_amdgcn_mfma_f32_16x16x32_bf16(
                        B[cur][nt], X[mt], acc[mt][nt], 0, 0, 0);
        }

        // epilogue 1: acc + Pr + Ps, relu, cvt_pk -> b64 swizzled Hs write
        #pragma unroll
        for (int nt = 0; nt < 4; ++nt) {
            const int F = wid * 64 + nt * 16 + q * 4;
            #pragma unroll
            for (int mt = 0; mt < 4; ++mt) {
                u32x2 p = pg[nt][mt], s = sg[nt][mt];
                float v0 = fmaxf(acc[mt][nt][0] + bflo(p.x) + bflo(s.x), 0.f);
                float v1 = fmaxf(acc[mt][nt][1] + bfhi(p.x) + bfhi(s.x), 0.f);
                float v2 = fmaxf(acc[mt][nt][2] + bflo(p.y) + bflo(s.y), 0.f);
                float v3 = fmaxf(acc[mt][nt][3] + bfhi(p.y) + bfhi(s.y), 0.f);
                u32x2 w = { cvt_pk_bf16(v0, v1), cvt_pk_bf16(v2, v3) };
                const int edge = mt * 16 + lr;
                *(u32x2*)&Hs[edge * 256 + (F ^ ((edge & 7) << 3))] = w;
            }
        }

        block_sync_lds();   // Hs ready; all waves' Xe(ti) reads complete

        // stage-write: Xe(tn) from er (compiler waits vmcnt on er here)
        #pragma unroll
        for (int p = 0; p < 4; ++p) {
            uint4 uu = { cvt_pk_bf16(er[2*p].x, er[2*p].y),  cvt_pk_bf16(er[2*p].z, er[2*p].w),
                         cvt_pk_bf16(er[2*p+1].x, er[2*p+1].y), cvt_pk_bf16(er[2*p+1].z, er[2*p+1].w) };
            *(bf16x8*)&Xe[sr[p] * 128 + (sc[p] ^ ((sr[p] & 7) << 3))] = __builtin_bit_cast(bf16x8, uu);
        }

        // prefetch tile tn2 = ti + 2*GRID (clamped): full-iteration latency
        int tn2 = ti + 2 * GRID; if (tn2 >= NTILE) tn2 = tn;
        #pragma unroll
        for (int p = 0; p < 4; ++p) {
            const float4* src = (const float4*)(edge_attr + (size_t)(tn2 * 64 + sr[p]) * 128 + sc[p]);
            er[2 * p]     = src[0];
            er[2 * p + 1] = src[1];
        }
        #pragma unroll
        for (int mt = 0; mt < 4; ++mt) {
            recvC[mt] = recvN[mt];
            sendC[mt] = sendN[mt];
            int e = tn2 * 64 + mt * 16 + lr;
            recvN[mt] = receivers[e];
            sendN[mt] = senders[e];
        }

        // GEMM2: D row = out feat, col = edge; K = 256 from Hs
        f32x4 acc2[4][2];
        #pragma unroll
        for (int mt = 0; mt < 4; ++mt)
            #pragma unroll
            for (int nt = 0; nt < 2; ++nt)
                acc2[mt][nt] = (f32x4){0.f, 0.f, 0.f, 0.f};

        bf16x8 W2b[2][2];
        #pragma unroll
        for (int nt = 0; nt < 2; ++nt)
            W2b[0][nt] = *(const bf16x8*)&w2f[(size_t)(((wid * 2 + nt) * 8 + 0) * 64 + l) * 8];

        #pragma unroll
        for (int ks = 0; ks < 8; ++ks) {
            const int cur = ks & 1;
            if (ks < 7) {
                #pragma unroll
                for (int nt = 0; nt < 2; ++nt)
                    W2b[cur ^ 1][nt] = *(const bf16x8*)&w2f[
                        (size_t)(((wid * 2 + nt) * 8 + (ks + 1)) * 64 + l) * 8];
            }
            bf16x8 Hfr[4];
            const int F = ks * 32 + lk;
            #pragma unroll
            for (int mt = 0; mt < 4; ++mt) {
                const int edge = mt * 16 + lr;
                Hfr[mt] = *(const bf16x8*)&Hs[edge * 256 + (F ^ ((edge & 7) << 3))];
            }
            #pragma unroll
            for (int mt = 0; mt < 4; ++mt)
                #pragma unroll
                for (int nt = 0; nt < 2; ++nt)
                    acc2[mt][nt] = __builtin_amdgcn_mfma_f32_16x16x32_bf16(
                        W2b[cur][nt], Hfr[mt], acc2[mt][nt], 0, 0, 0);
        }

        // epilogue 2: +b2, dwordx4 stores
        #pragma unroll
        for (int nt = 0; nt < 2; ++nt) {
            const int F = wid * 32 + nt * 16 + q * 4;
            float4 b24 = *(const float4*)&b2[F];
            #pragma unroll
            for (int mt = 0; mt < 4; ++mt) {
                float4 o = { acc2[mt][nt][0] + b24.x, acc2[mt][nt][1] + b24.y,
                             acc2[mt][nt][2] + b24.z, acc2[mt][nt][3] + b24.w };
                *(float4*)&out[(size_t)(ti * 64 + mt * 16 + lr) * 128 + F] = o;
            }
        }

        tn = tn2;
        block_sync_lds();   // Xe(next tile) visible before next GEMM1
    }
}

// ---------------- launcher ----------------

extern "C" void kernel_launch(void* const* d_in, const int* in_sizes, int n_in,
                              void* d_out, int out_size, void* d_ws, size_t ws_size,
                              hipStream_t stream) {
    (void)in_sizes; (void)n_in; (void)out_size; (void)ws_size;

    const float* edge_attr   = (const float*)d_in[0];  // [640000][128]
    const float* node_attr   = (const float*)d_in[1];  // [10000][128]
    const float* global_attr = (const float*)d_in[2];  // [128]
    const int*   senders     = (const int*)d_in[3];
    const int*   receivers   = (const int*)d_in[4];
    const float* W1          = (const float*)d_in[5];  // [512][256]
    const float* b1          = (const float*)d_in[6];  // [256]
    const float* W2          = (const float*)d_in[7];  // [256][128]
    const float* b2          = (const float*)d_in[8];  // [128]
    float* out = (float*)d_out;

    // workspace layout (all 16B aligned)
    ushort* w1f   = (ushort*)d_ws;                          //   196,608 B
    ushort* w2f   = (ushort*)((char*)d_ws + 196608);        //    65,536 B
    float*  hbias = (float*)((char*)d_ws + 262144);         //     1,024 B
    ushort* Pr    = (ushort*)((char*)d_ws + 263168);        // 5,120,000 B
    ushort* Ps    = (ushort*)((char*)d_ws + 5383168);       // 5,120,000 B

    hipLaunchKernelGGL(prep_w1_kernel,    dim3(48),  dim3(256), 0, stream, W1, w1f);
    hipLaunchKernelGGL(prep_w2_kernel,    dim3(16),  dim3(256), 0, stream, W2, w2f);
    hipLaunchKernelGGL(prep_hbias_kernel, dim3(1),   dim3(256), 0, stream, W1, b1, global_attr, hbias);
    hipLaunchKernelGGL(prep_proj_kernel,  dim3(157), dim3(256), 0, stream,
                       node_attr, w1f, hbias, Pr, Ps);

    hipLaunchKernelGGL(edge_mlp_kernel, dim3(GRID), dim3(256), 0, stream,
                       edge_attr, senders, receivers, w1f, w2f, Pr, Ps, b2, out);
}